// Round 2
// baseline (341.814 us; speedup 1.0000x reference)
//
#include <hip/hip_runtime.h>
#include <math.h>

#define N_CH    256
#define SBSHIFT 11             // super-bucket = 2048 nodes
#define SBN     2048
#define NSMAX   64             // actual ns = 49
#define CH      4096           // edges per chunk (input chunks AND output chunks)

__device__ __forceinline__ float sigmoidf_(float v) {
    return 1.0f / (1.0f + expf(-v));
}

// Build the 49-entry prefix tables from sbT in-block (thread 0 -> LDS).
__device__ __forceinline__ void build_tables(const int* sbT, int ns,
                                             int* sbsL, int* cstL) {
    if (threadIdx.x == 0) {
        int run = 0, c = 0;
        for (int i = 0; i < ns; ++i) {
            sbsL[i] = run;
            cstL[i] = c;
            int len = sbT[i];
            run += len;
            c += (len + CH - 1) / CH;
        }
        sbsL[ns] = run;
        cstL[ns] = c;
    }
}

// ---- K1 fused: blocks [0,nch): 8-way replicated 49-bin histogram of one input
// ---- chunk + direct global deg atomics; remaining blocks: per-node dots -----
__global__ __launch_bounds__(256) void dots_hist_kernel(
    const float* __restrict__ x,
    const float* __restrict__ Wmlp, const float* __restrict__ Wlin,
    const float* __restrict__ Wgcn, const int* __restrict__ dst,
    float* __restrict__ s2dot, float* __restrict__ s3lin, float* __restrict__ xw,
    int* __restrict__ H1, int* __restrict__ deg,
    int n_nodes, int n_edges, int ns, int nch)
{
    __shared__ int h8[NSMAX * 8];          // [bin*8 + copy]
    if ((int)blockIdx.x < nch) {
        int c = blockIdx.x;
        for (int i = threadIdx.x; i < NSMAX * 8; i += 256) h8[i] = 0;
        __syncthreads();
        int copy = (int)threadIdx.x & 7;
        int start = c * CH;
        #pragma unroll
        for (int m = 0; m < 4; ++m) {
            int e = start + (m * 256 + (int)threadIdx.x) * 4;
            if (e + 3 < n_edges) {
                int4 d4 = *(const int4*)(dst + e);
                atomicAdd(&h8[(d4.x >> SBSHIFT) * 8 + copy], 1);
                atomicAdd(&h8[(d4.y >> SBSHIFT) * 8 + copy], 1);
                atomicAdd(&h8[(d4.z >> SBSHIFT) * 8 + copy], 1);
                atomicAdd(&h8[(d4.w >> SBSHIFT) * 8 + copy], 1);
                atomicAdd(&deg[d4.x], 1);
                atomicAdd(&deg[d4.y], 1);
                atomicAdd(&deg[d4.z], 1);
                atomicAdd(&deg[d4.w], 1);
            } else {
                for (int ee = e; ee < n_edges && ee >= 0; ++ee) {
                    int d = dst[ee];
                    atomicAdd(&h8[(d >> SBSHIFT) * 8 + copy], 1);
                    atomicAdd(&deg[d], 1);
                }
            }
        }
        __syncthreads();
        if (threadIdx.x < (unsigned)ns) {
            int s = 0;
            #pragma unroll
            for (int k = 0; k < 8; ++k) s += h8[threadIdx.x * 8 + k];
            H1[(size_t)threadIdx.x * nch + c] = s;
        }
        return;
    }

    int wid  = ((int)blockIdx.x - nch) * 4 + ((int)threadIdx.x >> 6);
    int lane = threadIdx.x & 63;
    if (wid >= n_nodes) return;

    const float4* xr = (const float4*)(x + (size_t)wid * N_CH);
    float4 v  = xr[lane];
    float4 wm = ((const float4*)Wmlp)[lane];
    float4 wl = ((const float4*)Wlin)[lane];
    float4 wg = ((const float4*)Wgcn)[lane];

    float d0 = v.x*wm.x + v.y*wm.y + v.z*wm.z + v.w*wm.w;
    float d1 = v.x*wl.x + v.y*wl.y + v.z*wl.z + v.w*wl.w;
    float d2 = v.x*wg.x + v.y*wg.y + v.z*wg.z + v.w*wg.w;

    #pragma unroll
    for (int off = 32; off; off >>= 1) {
        d0 += __shfl_down(d0, off, 64);
        d1 += __shfl_down(d1, off, 64);
        d2 += __shfl_down(d2, off, 64);
    }
    if (lane == 0) { s2dot[wid] = d0; s3lin[wid] = d1; xw[wid] = d2; }
}

// ---- K2 scanA: per super-bucket exclusive scan of its input-chunk counts ----
__global__ __launch_bounds__(1024) void scanA_kernel(
    const int* __restrict__ H1, int* __restrict__ O, int* __restrict__ sbT,
    int nch)
{
    __shared__ int s[1024];
    int sb = blockIdx.x, t = threadIdx.x;
    int v = (t < nch) ? H1[(size_t)sb * nch + t] : 0;
    s[t] = v;
    __syncthreads();
    for (int off = 1; off < 1024; off <<= 1) {
        int a = s[t];
        int b = (t >= off) ? s[t - off] : 0;
        __syncthreads();
        s[t] = a + b;
        __syncthreads();
    }
    if (t < nch) O[(size_t)sb * nch + t] = s[t] - v;
    if (t == 1023) sbT[sb] = s[1023];
}

// ---- K3 scatter v2 (+ fused reduceDeg tail blocks) --------------------------
// Scatter blocks: lp loaded from H1 (no re-histogram), wave-0 shfl scans for
// lp and sbsL, sbOf position map replaces the flush binary search.
// cpack word: src (17 bits) | local11 (11 bits) << 17
__global__ __launch_bounds__(256) void scatter_deg_kernel(
    const int* __restrict__ src, const int* __restrict__ dst,
    const int* __restrict__ sbT, const int* __restrict__ O,
    const int* __restrict__ H1,
    const int* __restrict__ deg, const float* __restrict__ xw,
    float* __restrict__ degf, float* __restrict__ dinv, float* __restrict__ sxw,
    int* __restrict__ cpack, int n_nodes, int n_edges, int ns, int nch)
{
    if ((int)blockIdx.x >= nch) {
        // fused reduceDeg: elementwise per node
        int i = ((int)blockIdx.x - nch) * 256 + (int)threadIdx.x;
        if (i < n_nodes) {
            float df = (float)deg[i];
            degf[i] = df;
            float di = rsqrtf(df + 1.0f);    // GCN degree includes self-loop
            dinv[i] = di;
            sxw[i]  = di * xw[i];
        }
        return;
    }

    __shared__ int lp[NSMAX + 1];          // local (in-chunk) exclusive prefix
    __shared__ int dl[NSMAX];              // delta = pos0 - lp
    __shared__ int h2[NSMAX];              // rank counters
    __shared__ unsigned short sbOf[CH];    // position -> super-bucket map
    __shared__ int sorted[CH];             // 16 KB

    int c = blockIdx.x;
    int t = threadIdx.x;

    if (t < 64) {
        h2[t] = 0;
        int hv = (t < ns) ? H1[(size_t)t * nch + c] : 0;  // this chunk's count
        int sv = (t < ns) ? sbT[t] : 0;                   // sb total
        int hi = hv, si = sv;
        #pragma unroll
        for (int off = 1; off < 64; off <<= 1) {
            int a = __shfl_up(hi, off, 64); if (t >= off) hi += a;
            int b = __shfl_up(si, off, 64); if (t >= off) si += b;
        }
        if (t < ns) {
            int lpe = hi - hv;                    // exclusive in-chunk prefix
            lp[t] = lpe;
            int sbs = si - sv;                    // sbsL[t]
            dl[t] = sbs + O[(size_t)t * nch + c] - lpe;
        }
        if (t == ns - 1) lp[ns] = hi;             // = cnt
    }
    __syncthreads();

    // fill sbOf map (threads 0..ns-1, then all threads rank their edges)
    if (t < ns) {
        int p0 = lp[t], p1 = lp[t + 1];
        for (int p = p0; p < p1; ++p) sbOf[p] = (unsigned short)t;
    }

    int start = c * CH;
    int cnt = n_edges - start; if (cnt > CH) cnt = CH;

    #pragma unroll
    for (int m = 0; m < 4; ++m) {
        int e = start + (m * 256 + t) * 4;
        if (e + 3 < n_edges) {
            int4 s4 = *(const int4*)(src + e);
            int4 d4 = *(const int4*)(dst + e);
            int sb, r;
            sb = d4.x >> SBSHIFT; r = atomicAdd(&h2[sb], 1);
            sorted[lp[sb] + r] = s4.x | ((d4.x & (SBN - 1)) << 17);
            sb = d4.y >> SBSHIFT; r = atomicAdd(&h2[sb], 1);
            sorted[lp[sb] + r] = s4.y | ((d4.y & (SBN - 1)) << 17);
            sb = d4.z >> SBSHIFT; r = atomicAdd(&h2[sb], 1);
            sorted[lp[sb] + r] = s4.z | ((d4.z & (SBN - 1)) << 17);
            sb = d4.w >> SBSHIFT; r = atomicAdd(&h2[sb], 1);
            sorted[lp[sb] + r] = s4.w | ((d4.w & (SBN - 1)) << 17);
        } else {
            for (int j = 0; j < 4; ++j) {
                int ee = e + j;
                if (ee < n_edges && ee >= 0) {
                    int sv = src[ee], dv = dst[ee];
                    int sb = dv >> SBSHIFT;
                    int r = atomicAdd(&h2[sb], 1);
                    sorted[lp[sb] + r] = sv | ((dv & (SBN - 1)) << 17);
                }
            }
        }
    }
    __syncthreads();

    // coalesced flush: addr = dl[sb_of(p)] + p
    for (int p = t; p < cnt; p += 256) {
        cpack[dl[sbOf[p]] + p] = sorted[p];
    }
}

// ---- K6 chunkAcc: per output chunk, sum of sxw[src] -> dense partial row ----
__global__ __launch_bounds__(256) void chunkAcc_kernel(
    const int* __restrict__ cpack, const int* __restrict__ sbT,
    const float* __restrict__ sxw, float* __restrict__ partialF, int ns)
{
    __shared__ int sbsL[NSMAX + 1], cstL[NSMAX + 1];
    __shared__ float facc[SBN];
    build_tables(sbT, ns, sbsL, cstL);
    for (int i = threadIdx.x; i < SBN; i += 256) facc[i] = 0.0f;
    __syncthreads();
    int c = blockIdx.x;
    if (c >= cstL[ns]) return;
    int lo = 0, hi = ns;
    while (hi - lo > 1) { int mid = (lo + hi) >> 1; if (cstL[mid] <= c) lo = mid; else hi = mid; }
    int sb = lo;
    int i0 = c - cstL[sb];
    int base = sbsL[sb] + i0 * CH;
    int len = sbsL[sb + 1] - base; if (len > CH) len = CH;

    #pragma unroll
    for (int m = 0; m < 4; ++m) {
        int e = (m * 256 + (int)threadIdx.x) * 4;
        if (e + 3 < len) {
            int4 w4 = *(const int4*)(cpack + base + e);
            atomicAdd(&facc[w4.x >> 17], sxw[w4.x & 0x1FFFF]);
            atomicAdd(&facc[w4.y >> 17], sxw[w4.y & 0x1FFFF]);
            atomicAdd(&facc[w4.z >> 17], sxw[w4.z & 0x1FFFF]);
            atomicAdd(&facc[w4.w >> 17], sxw[w4.w & 0x1FFFF]);
        } else {
            for (int ee = e; ee < len && ee >= 0; ++ee) {
                int w = cpack[base + ee];
                atomicAdd(&facc[w >> 17], sxw[w & 0x1FFFF]);
            }
        }
    }
    __syncthreads();
    float* row = partialF + (size_t)c * SBN;
    for (int i = threadIdx.x; i < SBN; i += 256) row[i] = facc[i];
}

// ---- K7 reduceFinal: per-node accumulate + fused epilogue -------------------
__global__ __launch_bounds__(256) void reduceFinal_kernel(
    const float* __restrict__ partialF, const int* __restrict__ sbT,
    const float* __restrict__ degf, const float* __restrict__ dinv,
    const float* __restrict__ xw, const float* __restrict__ s2dot,
    const float* __restrict__ s3lin,
    const float* __restrict__ alpha, const float* __restrict__ beta,
    const float* __restrict__ Watt, const float* __restrict__ batt,
    float* __restrict__ out, int n_nodes, int ns)
{
    __shared__ int sbsL[NSMAX + 1], cstL[NSMAX + 1];
    build_tables(sbT, ns, sbsL, cstL);
    __syncthreads();
    int i = blockIdx.x * 256 + threadIdx.x;
    if (i >= n_nodes) return;
    int sb = i >> SBSHIFT, li = i & (SBN - 1);
    int c0 = cstL[sb], c1 = cstL[sb + 1];
    float acc = 0.0f;
    for (int c = c0; c < c1; ++c) acc += partialF[(size_t)c * SBN + li];

    float dn = dinv[i];
    float g  = acc * dn + dn * dn * xw[i];     // factored norm + self-loop
    float s1 = sigmoidf_(alpha[0] * sqrtf(degf[i]) + beta[0]);
    float s2 = sigmoidf_(s2dot[i]);
    float s3 = sigmoidf_(g + s3lin[i]);

    float z0 = Watt[0]*s1 + Watt[1]*s2 + Watt[2]*s3 + batt[0];
    float z1 = Watt[3]*s1 + Watt[4]*s2 + Watt[5]*s3 + batt[1];
    float z2 = Watt[6]*s1 + Watt[7]*s2 + Watt[8]*s3 + batt[2];

    float m  = fmaxf(z0, fmaxf(z1, z2));
    float e0 = expf(z0 - m), e1 = expf(z1 - m), e2 = expf(z2 - m);
    float inv = 1.0f / (e0 + e1 + e2);
    out[i] = (e0 * s1 + e1 * s2 + e2 * s3) * inv;
}

extern "C" void kernel_launch(void* const* d_in, const int* in_sizes, int n_in,
                              void* d_out, int out_size, void* d_ws, size_t ws_size,
                              hipStream_t stream) {
    const float* x     = (const float*)d_in[0];
    const int*   ei    = (const int*)d_in[1];
    const float* alpha = (const float*)d_in[2];
    const float* beta  = (const float*)d_in[3];
    const float* Wmlp  = (const float*)d_in[4];
    const float* Wlin  = (const float*)d_in[5];
    const float* Wgcn  = (const float*)d_in[6];
    const float* Watt  = (const float*)d_in[7];
    const float* batt  = (const float*)d_in[8];
    float* out = (float*)d_out;

    int n_nodes = in_sizes[0] / N_CH;
    int n_edges = in_sizes[1] / 2;
    const int* src = ei;
    const int* dst = ei + n_edges;

    int ns  = (n_nodes + SBN - 1) >> SBSHIFT;        // 49
    int nch = (n_edges + CH - 1) / CH;               // 782
    int maxChunks = nch + ns;                        // 831 (output chunk bound)

    // ws layout (4-byte elements, 1024-aligned regions)
    size_t off = 0;
    int*   cpack    = (int*)d_ws;          off += (((size_t)n_edges + 1023) & ~(size_t)1023);
    int*   H1       = (int*)d_ws + off;    off += (((size_t)ns * nch + 1023) & ~(size_t)1023);
    int*   O        = (int*)d_ws + off;    off += (((size_t)ns * nch + 1023) & ~(size_t)1023);
    int*   sbT      = (int*)d_ws + off;    off += 128;
    int*   deg      = (int*)d_ws + off;    off += (((size_t)n_nodes + 1023) & ~(size_t)1023);
    float* partialF = (float*)d_ws + off;  off += (size_t)maxChunks * SBN;
    float* s2dot    = (float*)d_ws + off;  off += (((size_t)n_nodes + 1023) & ~(size_t)1023);
    float* s3lin    = (float*)d_ws + off;  off += (((size_t)n_nodes + 1023) & ~(size_t)1023);
    float* xw       = (float*)d_ws + off;  off += (((size_t)n_nodes + 1023) & ~(size_t)1023);
    float* degf     = (float*)d_ws + off;  off += (((size_t)n_nodes + 1023) & ~(size_t)1023);
    float* dinv     = (float*)d_ws + off;  off += (((size_t)n_nodes + 1023) & ~(size_t)1023);
    float* sxw      = (float*)d_ws + off;  off += (((size_t)n_nodes + 1023) & ~(size_t)1023);

    hipMemsetAsync(deg, 0, (size_t)n_nodes * sizeof(int), stream);

    int dotsBlocks = (n_nodes + 3) / 4;
    dots_hist_kernel<<<nch + dotsBlocks, 256, 0, stream>>>(
        x, Wmlp, Wlin, Wgcn, dst, s2dot, s3lin, xw, H1, deg,
        n_nodes, n_edges, ns, nch);

    scanA_kernel<<<ns, 1024, 0, stream>>>(H1, O, sbT, nch);

    int degBlocks = (n_nodes + 255) / 256;
    scatter_deg_kernel<<<nch + degBlocks, 256, 0, stream>>>(
        src, dst, sbT, O, H1, deg, xw, degf, dinv, sxw, cpack,
        n_nodes, n_edges, ns, nch);

    chunkAcc_kernel<<<maxChunks, 256, 0, stream>>>(cpack, sbT, sxw, partialF, ns);

    reduceFinal_kernel<<<(n_nodes + 255) / 256, 256, 0, stream>>>(
        partialF, sbT, degf, dinv, xw, s2dot, s3lin,
        alpha, beta, Watt, batt, out, n_nodes, ns);
}

// Round 3
// 232.411 us; speedup vs baseline: 1.4707x; 1.4707x over previous
//
#include <hip/hip_runtime.h>
#include <math.h>

#define N_CH    256
#define SBSHIFT 11             // super-bucket = 2048 nodes
#define SBN     2048
#define NSMAX   64             // actual ns = 49
#define CH      4096           // edges per chunk (input chunks AND output chunks)

__device__ __forceinline__ float sigmoidf_(float v) {
    return 1.0f / (1.0f + expf(-v));
}

// Build the 49-entry prefix tables from sbT in-block (thread 0 -> LDS).
__device__ __forceinline__ void build_tables(const int* sbT, int ns,
                                             int* sbsL, int* cstL) {
    if (threadIdx.x == 0) {
        int run = 0, c = 0;
        for (int i = 0; i < ns; ++i) {
            sbsL[i] = run;
            cstL[i] = c;
            int len = sbT[i];
            run += len;
            c += (len + CH - 1) / CH;
        }
        sbsL[ns] = run;
        cstL[ns] = c;
    }
}

// ---- K1 fused: blocks [0,nch): 8-way replicated 49-bin histogram of one input
// ---- chunk; remaining blocks: three per-node dot products (1 wave/node) -----
// NOTE: no global deg atomics — R2 showed 3.2M device-scope atomicAdds cost
// ~100us and 103MB of HBM writes (32B RMW write-through past non-coherent L2s).
__global__ __launch_bounds__(256) void dots_hist_kernel(
    const float* __restrict__ x,
    const float* __restrict__ Wmlp, const float* __restrict__ Wlin,
    const float* __restrict__ Wgcn, const int* __restrict__ dst,
    float* __restrict__ s2dot, float* __restrict__ s3lin, float* __restrict__ xw,
    int* __restrict__ H1,
    int n_nodes, int n_edges, int ns, int nch)
{
    __shared__ int h8[NSMAX * 8];          // [bin*8 + copy]
    if ((int)blockIdx.x < nch) {
        int c = blockIdx.x;
        for (int i = threadIdx.x; i < NSMAX * 8; i += 256) h8[i] = 0;
        __syncthreads();
        int copy = (int)threadIdx.x & 7;
        int start = c * CH;
        #pragma unroll
        for (int m = 0; m < 4; ++m) {
            int e = start + (m * 256 + (int)threadIdx.x) * 4;
            if (e + 3 < n_edges) {
                int4 d4 = *(const int4*)(dst + e);
                atomicAdd(&h8[(d4.x >> SBSHIFT) * 8 + copy], 1);
                atomicAdd(&h8[(d4.y >> SBSHIFT) * 8 + copy], 1);
                atomicAdd(&h8[(d4.z >> SBSHIFT) * 8 + copy], 1);
                atomicAdd(&h8[(d4.w >> SBSHIFT) * 8 + copy], 1);
            } else {
                for (int ee = e; ee < n_edges && ee >= 0; ++ee)
                    atomicAdd(&h8[(dst[ee] >> SBSHIFT) * 8 + copy], 1);
            }
        }
        __syncthreads();
        if (threadIdx.x < (unsigned)ns) {
            int s = 0;
            #pragma unroll
            for (int k = 0; k < 8; ++k) s += h8[threadIdx.x * 8 + k];
            H1[(size_t)threadIdx.x * nch + c] = s;
        }
        return;
    }

    int wid  = ((int)blockIdx.x - nch) * 4 + ((int)threadIdx.x >> 6);
    int lane = threadIdx.x & 63;
    if (wid >= n_nodes) return;

    const float4* xr = (const float4*)(x + (size_t)wid * N_CH);
    float4 v  = xr[lane];
    float4 wm = ((const float4*)Wmlp)[lane];
    float4 wl = ((const float4*)Wlin)[lane];
    float4 wg = ((const float4*)Wgcn)[lane];

    float d0 = v.x*wm.x + v.y*wm.y + v.z*wm.z + v.w*wm.w;
    float d1 = v.x*wl.x + v.y*wl.y + v.z*wl.z + v.w*wl.w;
    float d2 = v.x*wg.x + v.y*wg.y + v.z*wg.z + v.w*wg.w;

    #pragma unroll
    for (int off = 32; off; off >>= 1) {
        d0 += __shfl_down(d0, off, 64);
        d1 += __shfl_down(d1, off, 64);
        d2 += __shfl_down(d2, off, 64);
    }
    if (lane == 0) { s2dot[wid] = d0; s3lin[wid] = d1; xw[wid] = d2; }
}

// ---- K2 scanA: per super-bucket exclusive scan of its input-chunk counts ----
__global__ __launch_bounds__(1024) void scanA_kernel(
    const int* __restrict__ H1, int* __restrict__ O, int* __restrict__ sbT,
    int nch)
{
    __shared__ int s[1024];
    int sb = blockIdx.x, t = threadIdx.x;
    int v = (t < nch) ? H1[(size_t)sb * nch + t] : 0;
    s[t] = v;
    __syncthreads();
    for (int off = 1; off < 1024; off <<= 1) {
        int a = s[t];
        int b = (t >= off) ? s[t - off] : 0;
        __syncthreads();
        s[t] = a + b;
        __syncthreads();
    }
    if (t < nch) O[(size_t)sb * nch + t] = s[t] - v;
    if (t == 1023) sbT[sb] = s[1023];
}

// ---- K3 scatter v2: lp from H1 (no re-histogram), wave-0 shfl scans, sbOf
// ---- position map replaces the flush binary search --------------------------
// cpack word: src (17 bits) | local11 (11 bits) << 17
__global__ __launch_bounds__(256) void scatter_kernel(
    const int* __restrict__ src, const int* __restrict__ dst,
    const int* __restrict__ sbT, const int* __restrict__ O,
    const int* __restrict__ H1,
    int* __restrict__ cpack, int n_edges, int ns, int nch)
{
    __shared__ int lp[NSMAX + 1];          // local (in-chunk) exclusive prefix
    __shared__ int dl[NSMAX];              // delta = pos0 - lp
    __shared__ int h2[NSMAX];              // rank counters
    __shared__ unsigned short sbOf[CH];    // position -> super-bucket map
    __shared__ int sorted[CH];             // 16 KB

    int c = blockIdx.x;
    int t = threadIdx.x;

    if (t < 64) {
        h2[t] = 0;
        int hv = (t < ns) ? H1[(size_t)t * nch + c] : 0;  // this chunk's count
        int sv = (t < ns) ? sbT[t] : 0;                   // sb total
        int hi = hv, si = sv;
        #pragma unroll
        for (int off = 1; off < 64; off <<= 1) {
            int a = __shfl_up(hi, off, 64); if (t >= off) hi += a;
            int b = __shfl_up(si, off, 64); if (t >= off) si += b;
        }
        if (t < ns) {
            int lpe = hi - hv;                    // exclusive in-chunk prefix
            lp[t] = lpe;
            int sbs = si - sv;                    // sbsL[t]
            dl[t] = sbs + O[(size_t)t * nch + c] - lpe;
        }
        if (t == ns - 1) lp[ns] = hi;             // = cnt
    }
    __syncthreads();

    // fill sbOf map (threads 0..ns-1); other threads proceed to load edges
    if (t < ns) {
        int p0 = lp[t], p1 = lp[t + 1];
        for (int p = p0; p < p1; ++p) sbOf[p] = (unsigned short)t;
    }

    int start = c * CH;
    int cnt = n_edges - start; if (cnt > CH) cnt = CH;

    #pragma unroll
    for (int m = 0; m < 4; ++m) {
        int e = start + (m * 256 + t) * 4;
        if (e + 3 < n_edges) {
            int4 s4 = *(const int4*)(src + e);
            int4 d4 = *(const int4*)(dst + e);
            int sb, r;
            sb = d4.x >> SBSHIFT; r = atomicAdd(&h2[sb], 1);
            sorted[lp[sb] + r] = s4.x | ((d4.x & (SBN - 1)) << 17);
            sb = d4.y >> SBSHIFT; r = atomicAdd(&h2[sb], 1);
            sorted[lp[sb] + r] = s4.y | ((d4.y & (SBN - 1)) << 17);
            sb = d4.z >> SBSHIFT; r = atomicAdd(&h2[sb], 1);
            sorted[lp[sb] + r] = s4.z | ((d4.z & (SBN - 1)) << 17);
            sb = d4.w >> SBSHIFT; r = atomicAdd(&h2[sb], 1);
            sorted[lp[sb] + r] = s4.w | ((d4.w & (SBN - 1)) << 17);
        } else {
            for (int j = 0; j < 4; ++j) {
                int ee = e + j;
                if (ee < n_edges && ee >= 0) {
                    int sv = src[ee], dv = dst[ee];
                    int sb = dv >> SBSHIFT;
                    int r = atomicAdd(&h2[sb], 1);
                    sorted[lp[sb] + r] = sv | ((dv & (SBN - 1)) << 17);
                }
            }
        }
    }
    __syncthreads();

    // coalesced flush: addr = dl[sb_of(p)] + p
    for (int p = t; p < cnt; p += 256) {
        cpack[dl[sbOf[p]] + p] = sorted[p];
    }
}

// ---- K4 chunkDeg: per output chunk, node counts -> dense partial row --------
__global__ __launch_bounds__(256) void chunkDeg_kernel(
    const int* __restrict__ cpack, const int* __restrict__ sbT,
    int* __restrict__ partialD, int ns)
{
    __shared__ int sbsL[NSMAX + 1], cstL[NSMAX + 1];
    __shared__ int cnt[SBN];
    build_tables(sbT, ns, sbsL, cstL);
    for (int i = threadIdx.x; i < SBN; i += 256) cnt[i] = 0;
    __syncthreads();
    int c = blockIdx.x;
    if (c >= cstL[ns]) return;
    // find sb: cstL[sb] <= c < cstL[sb+1]
    int lo = 0, hi = ns;
    while (hi - lo > 1) { int mid = (lo + hi) >> 1; if (cstL[mid] <= c) lo = mid; else hi = mid; }
    int sb = lo;
    int i0 = c - cstL[sb];
    int base = sbsL[sb] + i0 * CH;
    int len = sbsL[sb + 1] - base; if (len > CH) len = CH;

    #pragma unroll
    for (int m = 0; m < 4; ++m) {
        int e = (m * 256 + (int)threadIdx.x) * 4;
        if (e + 3 < len) {
            int4 w4 = *(const int4*)(cpack + base + e);
            atomicAdd(&cnt[w4.x >> 17], 1);
            atomicAdd(&cnt[w4.y >> 17], 1);
            atomicAdd(&cnt[w4.z >> 17], 1);
            atomicAdd(&cnt[w4.w >> 17], 1);
        } else {
            for (int ee = e; ee < len && ee >= 0; ++ee)
                atomicAdd(&cnt[cpack[base + ee] >> 17], 1);
        }
    }
    __syncthreads();
    int* row = partialD + (size_t)c * SBN;
    for (int i = threadIdx.x; i < SBN; i += 256) row[i] = cnt[i];
}

// ---- K5 reduceDeg: per-node degree -> degf, dinv, sxw -----------------------
__global__ __launch_bounds__(256) void reduceDeg_kernel(
    const int* __restrict__ partialD, const int* __restrict__ sbT,
    const float* __restrict__ xw,
    float* __restrict__ degf, float* __restrict__ dinv, float* __restrict__ sxw,
    int n_nodes, int ns)
{
    __shared__ int sbsL[NSMAX + 1], cstL[NSMAX + 1];
    build_tables(sbT, ns, sbsL, cstL);
    __syncthreads();
    int i = blockIdx.x * 256 + threadIdx.x;
    if (i >= n_nodes) return;
    int sb = i >> SBSHIFT, li = i & (SBN - 1);
    int c0 = cstL[sb], c1 = cstL[sb + 1];
    int d = 0;
    for (int c = c0; c < c1; ++c) d += partialD[(size_t)c * SBN + li];
    float df = (float)d;
    degf[i] = df;
    float di = rsqrtf(df + 1.0f);        // GCN degree includes self-loop
    dinv[i] = di;
    sxw[i]  = di * xw[i];
}

// ---- K6 chunkAcc: per output chunk, sum of sxw[src] -> dense partial row ----
__global__ __launch_bounds__(256) void chunkAcc_kernel(
    const int* __restrict__ cpack, const int* __restrict__ sbT,
    const float* __restrict__ sxw, float* __restrict__ partialF, int ns)
{
    __shared__ int sbsL[NSMAX + 1], cstL[NSMAX + 1];
    __shared__ float facc[SBN];
    build_tables(sbT, ns, sbsL, cstL);
    for (int i = threadIdx.x; i < SBN; i += 256) facc[i] = 0.0f;
    __syncthreads();
    int c = blockIdx.x;
    if (c >= cstL[ns]) return;
    int lo = 0, hi = ns;
    while (hi - lo > 1) { int mid = (lo + hi) >> 1; if (cstL[mid] <= c) lo = mid; else hi = mid; }
    int sb = lo;
    int i0 = c - cstL[sb];
    int base = sbsL[sb] + i0 * CH;
    int len = sbsL[sb + 1] - base; if (len > CH) len = CH;

    #pragma unroll
    for (int m = 0; m < 4; ++m) {
        int e = (m * 256 + (int)threadIdx.x) * 4;
        if (e + 3 < len) {
            int4 w4 = *(const int4*)(cpack + base + e);
            atomicAdd(&facc[w4.x >> 17], sxw[w4.x & 0x1FFFF]);
            atomicAdd(&facc[w4.y >> 17], sxw[w4.y & 0x1FFFF]);
            atomicAdd(&facc[w4.z >> 17], sxw[w4.z & 0x1FFFF]);
            atomicAdd(&facc[w4.w >> 17], sxw[w4.w & 0x1FFFF]);
        } else {
            for (int ee = e; ee < len && ee >= 0; ++ee) {
                int w = cpack[base + ee];
                atomicAdd(&facc[w >> 17], sxw[w & 0x1FFFF]);
            }
        }
    }
    __syncthreads();
    float* row = partialF + (size_t)c * SBN;
    for (int i = threadIdx.x; i < SBN; i += 256) row[i] = facc[i];
}

// ---- K7 reduceFinal: per-node accumulate + fused epilogue -------------------
__global__ __launch_bounds__(256) void reduceFinal_kernel(
    const float* __restrict__ partialF, const int* __restrict__ sbT,
    const float* __restrict__ degf, const float* __restrict__ dinv,
    const float* __restrict__ xw, const float* __restrict__ s2dot,
    const float* __restrict__ s3lin,
    const float* __restrict__ alpha, const float* __restrict__ beta,
    const float* __restrict__ Watt, const float* __restrict__ batt,
    float* __restrict__ out, int n_nodes, int ns)
{
    __shared__ int sbsL[NSMAX + 1], cstL[NSMAX + 1];
    build_tables(sbT, ns, sbsL, cstL);
    __syncthreads();
    int i = blockIdx.x * 256 + threadIdx.x;
    if (i >= n_nodes) return;
    int sb = i >> SBSHIFT, li = i & (SBN - 1);
    int c0 = cstL[sb], c1 = cstL[sb + 1];
    float acc = 0.0f;
    for (int c = c0; c < c1; ++c) acc += partialF[(size_t)c * SBN + li];

    float dn = dinv[i];
    float g  = acc * dn + dn * dn * xw[i];     // factored norm + self-loop
    float s1 = sigmoidf_(alpha[0] * sqrtf(degf[i]) + beta[0]);
    float s2 = sigmoidf_(s2dot[i]);
    float s3 = sigmoidf_(g + s3lin[i]);

    float z0 = Watt[0]*s1 + Watt[1]*s2 + Watt[2]*s3 + batt[0];
    float z1 = Watt[3]*s1 + Watt[4]*s2 + Watt[5]*s3 + batt[1];
    float z2 = Watt[6]*s1 + Watt[7]*s2 + Watt[8]*s3 + batt[2];

    float m  = fmaxf(z0, fmaxf(z1, z2));
    float e0 = expf(z0 - m), e1 = expf(z1 - m), e2 = expf(z2 - m);
    float inv = 1.0f / (e0 + e1 + e2);
    out[i] = (e0 * s1 + e1 * s2 + e2 * s3) * inv;
}

extern "C" void kernel_launch(void* const* d_in, const int* in_sizes, int n_in,
                              void* d_out, int out_size, void* d_ws, size_t ws_size,
                              hipStream_t stream) {
    const float* x     = (const float*)d_in[0];
    const int*   ei    = (const int*)d_in[1];
    const float* alpha = (const float*)d_in[2];
    const float* beta  = (const float*)d_in[3];
    const float* Wmlp  = (const float*)d_in[4];
    const float* Wlin  = (const float*)d_in[5];
    const float* Wgcn  = (const float*)d_in[6];
    const float* Watt  = (const float*)d_in[7];
    const float* batt  = (const float*)d_in[8];
    float* out = (float*)d_out;

    int n_nodes = in_sizes[0] / N_CH;
    int n_edges = in_sizes[1] / 2;
    const int* src = ei;
    const int* dst = ei + n_edges;

    int ns  = (n_nodes + SBN - 1) >> SBSHIFT;        // 49
    int nch = (n_edges + CH - 1) / CH;               // 782
    int maxChunks = nch + ns;                        // 831 (output chunk bound)

    // ws layout (4-byte elements, 1024-aligned regions)
    size_t off = 0;
    int*   cpack    = (int*)d_ws;          off += (((size_t)n_edges + 1023) & ~(size_t)1023);
    int*   H1       = (int*)d_ws + off;    off += (((size_t)ns * nch + 1023) & ~(size_t)1023);
    int*   O        = (int*)d_ws + off;    off += (((size_t)ns * nch + 1023) & ~(size_t)1023);
    int*   sbT      = (int*)d_ws + off;    off += 128;
    int*   partialD = (int*)d_ws + off;    off += (size_t)maxChunks * SBN;
    float* partialF = (float*)d_ws + off;  off += (size_t)maxChunks * SBN;
    float* s2dot    = (float*)d_ws + off;  off += (((size_t)n_nodes + 1023) & ~(size_t)1023);
    float* s3lin    = (float*)d_ws + off;  off += (((size_t)n_nodes + 1023) & ~(size_t)1023);
    float* xw       = (float*)d_ws + off;  off += (((size_t)n_nodes + 1023) & ~(size_t)1023);
    float* degf     = (float*)d_ws + off;  off += (((size_t)n_nodes + 1023) & ~(size_t)1023);
    float* dinv     = (float*)d_ws + off;  off += (((size_t)n_nodes + 1023) & ~(size_t)1023);
    float* sxw      = (float*)d_ws + off;  off += (((size_t)n_nodes + 1023) & ~(size_t)1023);

    int dotsBlocks = (n_nodes + 3) / 4;
    dots_hist_kernel<<<nch + dotsBlocks, 256, 0, stream>>>(
        x, Wmlp, Wlin, Wgcn, dst, s2dot, s3lin, xw, H1,
        n_nodes, n_edges, ns, nch);

    scanA_kernel<<<ns, 1024, 0, stream>>>(H1, O, sbT, nch);

    scatter_kernel<<<nch, 256, 0, stream>>>(src, dst, sbT, O, H1, cpack,
                                            n_edges, ns, nch);

    chunkDeg_kernel<<<maxChunks, 256, 0, stream>>>(cpack, sbT, partialD, ns);

    reduceDeg_kernel<<<(n_nodes + 255) / 256, 256, 0, stream>>>(
        partialD, sbT, xw, degf, dinv, sxw, n_nodes, ns);

    chunkAcc_kernel<<<maxChunks, 256, 0, stream>>>(cpack, sbT, sxw, partialF, ns);

    reduceFinal_kernel<<<(n_nodes + 255) / 256, 256, 0, stream>>>(
        partialF, sbT, degf, dinv, xw, s2dot, s3lin,
        alpha, beta, Watt, batt, out, n_nodes, ns);
}